// Round 7
// baseline (77.655 us; speedup 1.0000x reference)
//
#include <hip/hip_runtime.h>
#include <math.h>

#define N_ANCH 10647
#define N_GT   2048
#define N_OUTC 85
#define PRED_ELEMS (N_ANCH * N_OUTC)   // 904995
#define PRED_V4    (PRED_ELEMS / 4)    // 226248 (3 tail floats)
#define N_CHUNK    42                  // ceil(10647/256)
#define NBMW       333                 // bitmap words: ceil(10647/32)

// k_iou geometry: 64-entry LDS chunks, ILP-2, big grid for occupancy
#define ABX 21                         // anchor side: 21 x 512 anchors (2/thread)
#define ABY 32                         //              32 x 64-GT chunks
#define NBLK_A (ABX * ABY)             // 672
#define GBX 4                          // gt side: 4 x 512 GTs (2/thread)
#define GBY 167                        //          167 x 64-anchor chunks (pad tail)
#define NBLK_G (GBX * GBY)             // 668
#define NBLK_IOU (NBLK_A + NBLK_G)     // 1340
#define CPY_PER_BLK ((PRED_V4 + NBLK_IOU - 1) / NBLK_IOU)   // 169

struct WS {
    unsigned long long akey[N_ANCH];   // packed (iou_bits<<32)|~gt_idx   (memset 0)
    unsigned long long gkey[N_GT];     // packed (iou_bits<<32)|~anchor_idx (memset 0)
};
#define MEMSET_BYTES ((N_ANCH + N_GT) * 8)

__device__ __forceinline__ float bce(float x, float t) {
    // matches: max(x,0) - x*t + log1p(exp(-|x|))
    return fmaxf(x, 0.0f) - x * t + log1pf(expf(-fabsf(x)));
}

__device__ __forceinline__ unsigned long long packkey(float iou, int idx) {
    return ((unsigned long long)__float_as_uint(iou) << 32) |
           (unsigned)(~(unsigned)idx);
}

// ---------------- K1: pred->out copy + fused IoU reductions ----------------
// Argmax state per slot: (I=inter, S=areaA+areaB, idx); iou = I/(S-I).
// Compare via cross-mult (monotone, denominators > 0); one IEEE div for the
// winner -> bitwise == reference iou value.
__global__ __launch_bounds__(256) void k_iou(const float* __restrict__ pred,
                                             const float* __restrict__ gtb,
                                             const float* __restrict__ priors,
                                             float* __restrict__ out,
                                             WS* __restrict__ ws) {
    int b = blockIdx.x, t = threadIdx.x;
    // distributed pred -> out copy (1 float4 per thread)
    if (t < CPY_PER_BLK) {
        int idx = b * CPY_PER_BLK + t;
        if (idx < PRED_V4)
            ((float4*)out)[idx] = ((const float4*)pred)[idx];
    }
    if (b == 0 && t == 0) {
        out[PRED_ELEMS - 3] = pred[PRED_ELEMS - 3];
        out[PRED_ELEMS - 2] = pred[PRED_ELEMS - 2];
        out[PRED_ELEMS - 1] = pred[PRED_ELEMS - 1];
        out[PRED_ELEMS] = 0.0f;        // k_tail atomicAdds into this
    }

    __shared__ float4 sc[64];
    __shared__ float  sa[64];

    if (b < NBLK_A) {
        // ---- anchor side: 2 anchors/thread vs 64 GTs in LDS ----
        int bx = b % ABX, by = b / ABX;
        int jbase = by * 64;
        if (t < 64) {
            float4 v = ((const float4*)gtb)[jbase + t];
            float4 c = make_float4(v.x - v.z*0.5f, v.y - v.w*0.5f,
                                   v.x + v.z*0.5f, v.y + v.w*0.5f);
            sc[t] = c;
            sa[t] = (c.z - c.x) * (c.w - c.y);
        }
        int i0 = bx * 512 + t, i1 = i0 + 256;
        bool v0 = (i0 < N_ANCH), v1 = (i1 < N_ANCH);
        float4 a0 = make_float4(0.f,0.f,0.f,0.f), a1 = a0;
        float aa0 = 0.f, aa1 = 0.f;
        if (v0) {
            float cx = priors[i0*N_OUTC+0], cy = priors[i0*N_OUTC+1];
            float w  = priors[i0*N_OUTC+2], h  = priors[i0*N_OUTC+3];
            a0 = make_float4(cx - w*0.5f, cy - h*0.5f, cx + w*0.5f, cy + h*0.5f);
            aa0 = (a0.z - a0.x) * (a0.w - a0.y);
        }
        if (v1) {
            float cx = priors[i1*N_OUTC+0], cy = priors[i1*N_OUTC+1];
            float w  = priors[i1*N_OUTC+2], h  = priors[i1*N_OUTC+3];
            a1 = make_float4(cx - w*0.5f, cy - h*0.5f, cx + w*0.5f, cy + h*0.5f);
            aa1 = (a1.z - a1.x) * (a1.w - a1.y);
        }
        __syncthreads();
        float I0 = -1.f, S0 = 1.f, I1 = -1.f, S1 = 1.f;
        int bj0 = 0, bj1 = 0;
#pragma unroll 4
        for (int jj = 0; jj < 64; ++jj) {
            float4 g = sc[jj]; float ga = sa[jj];
            float lx = fmaxf(a0.x, g.x), ly = fmaxf(a0.y, g.y);
            float rx = fminf(a0.z, g.z), ry = fminf(a0.w, g.w);
            float In = fmaxf(rx - lx, 0.f) * fmaxf(ry - ly, 0.f);
            float Sn = aa0 + ga;
            bool c = In * S0 > I0 * Sn;      // strict: first index on ties
            I0 = c ? In : I0; S0 = c ? Sn : S0; bj0 = c ? jj : bj0;
            lx = fmaxf(a1.x, g.x); ly = fmaxf(a1.y, g.y);
            rx = fminf(a1.z, g.z); ry = fminf(a1.w, g.w);
            In = fmaxf(rx - lx, 0.f) * fmaxf(ry - ly, 0.f);
            Sn = aa1 + ga;
            c = In * S1 > I1 * Sn;
            I1 = c ? In : I1; S1 = c ? Sn : S1; bj1 = c ? jj : bj1;
        }
        if (v0) atomicMax(&ws->akey[i0], packkey(I0 / (S0 - I0), jbase + bj0));
        if (v1) atomicMax(&ws->akey[i1], packkey(I1 / (S1 - I1), jbase + bj1));
    } else {
        // ---- gt side: 2 GTs/thread vs 64 anchors in LDS ----
        int b2 = b - NBLK_A;
        int bx = b2 % GBX, by = b2 / GBX;
        int ibase = by * 64;
        if (t < 64) {
            int i = ibase + t;
            float4 c = make_float4(0.f, 0.f, 0.f, 0.f);
            float ar = 0.f;
            if (i < N_ANCH) {
                float cx = priors[i*N_OUTC+0], cy = priors[i*N_OUTC+1];
                float w  = priors[i*N_OUTC+2], h  = priors[i*N_OUTC+3];
                c = make_float4(cx - w*0.5f, cy - h*0.5f, cx + w*0.5f, cy + h*0.5f);
                ar = (c.z - c.x) * (c.w - c.y);
            }
            // pads: I=0 -> never wins the strict cross-mult compare vs a real
            // earlier candidate with I >= 0.
            sc[t] = c; sa[t] = ar;
        }
        int j0 = bx * 512 + t, j1 = j0 + 256;
        float4 v = ((const float4*)gtb)[j0];
        float4 g0 = make_float4(v.x - v.z*0.5f, v.y - v.w*0.5f,
                                v.x + v.z*0.5f, v.y + v.w*0.5f);
        float ga0 = (g0.z - g0.x) * (g0.w - g0.y);
        v = ((const float4*)gtb)[j1];
        float4 g1 = make_float4(v.x - v.z*0.5f, v.y - v.w*0.5f,
                                v.x + v.z*0.5f, v.y + v.w*0.5f);
        float ga1 = (g1.z - g1.x) * (g1.w - g1.y);
        __syncthreads();
        float I0 = -1.f, S0 = 1.f, I1 = -1.f, S1 = 1.f;
        int bi0 = 0, bi1 = 0;
#pragma unroll 4
        for (int ii = 0; ii < 64; ++ii) {
            float4 a = sc[ii]; float aa = sa[ii];
            float lx = fmaxf(a.x, g0.x), ly = fmaxf(a.y, g0.y);
            float rx = fminf(a.z, g0.z), ry = fminf(a.w, g0.w);
            float In = fmaxf(rx - lx, 0.f) * fmaxf(ry - ly, 0.f);
            float Sn = aa + ga0;
            bool c = In * S0 > I0 * Sn;
            I0 = c ? In : I0; S0 = c ? Sn : S0; bi0 = c ? ii : bi0;
            lx = fmaxf(a.x, g1.x); ly = fmaxf(a.y, g1.y);
            rx = fminf(a.z, g1.z); ry = fminf(a.w, g1.w);
            In = fmaxf(rx - lx, 0.f) * fmaxf(ry - ly, 0.f);
            Sn = aa + ga1;
            c = In * S1 > I1 * Sn;
            I1 = c ? In : I1; S1 = c ? Sn : S1; bi1 = c ? ii : bi1;
        }
        atomicMax(&ws->gkey[j0], packkey(I0 / (S0 - I0), ibase + bi0));
        atomicMax(&ws->gkey[j1], packkey(I1 / (S1 - I1), ibase + bi1));
    }
}

// ---------------- K2: fused tail — labels, global counts, demote-first,
//                  column-parallel loss, normalized atomic accumulate -------
// 42 blocks; each block redundantly derives the GLOBAL counts from akey/gkey
// (101 KB, L3-hot after k_iou), so no intermediate tiny kernels are needed.
__global__ __launch_bounds__(256) void k_tail(const float* __restrict__ pred,
                                              const float* __restrict__ gtb,
                                              const int* __restrict__ gtl,
                                              WS* __restrict__ ws,
                                              float* __restrict__ out) {
    __shared__ unsigned fbm[NBMW];     // global is_gt_max bitmap
    __shared__ int wA[4], wB[4], wC[4], wD[4];
    __shared__ int wps[4], wns[4];
    __shared__ int    sPosI[256];
    __shared__ float4 sPosBox[256];
    __shared__ int    sPosCls[256];
    __shared__ int    sNegI[256];
    __shared__ float  red[12];
    int b = blockIdx.x, t = threadIdx.x, lane = t & 63, wid = t >> 6;

    for (int k = t; k < NBMW; k += 256) fbm[k] = 0u;
    __syncthreads();
    for (int j = t; j < N_GT; j += 256) {
        unsigned ai = ~(unsigned)(ws->gkey[j]);
        atomicOr(&fbm[ai >> 5], 1u << (ai & 31));
    }
    __syncthreads();

    // global count pass: all 42 chunks, per-wave ballots (no barriers)
    const unsigned* akhi = ((const unsigned*)ws->akey) + 1;   // hi words, stride 2
    int npaW = 0, nnaW = 0, pbW = 0, nbW = 0;
    for (int c = 0; c < N_CHUNK; ++c) {
        int i = c * 256 + t;
        int lab = -2;
        if (i < N_ANCH) {
            float amax = __uint_as_float(akhi[2 * i]);
            bool fl = (fbm[i >> 5] >> (i & 31)) & 1u;
            lab = (amax < 0.3f) ? 0 : ((amax >= 0.7f || fl) ? 1 : -1);
        }
        int c1 = __popcll(__ballot(lab == 1));
        int c0 = __popcll(__ballot(lab == 0));
        npaW += c1; nnaW += c0;
        if (c < b) { pbW += c1; nbW += c0; }
    }
    if (lane == 0) { wA[wid] = npaW; wB[wid] = nnaW; wC[wid] = pbW; wD[wid] = nbW; }
    __syncthreads();
    int npa = wA[0]+wA[1]+wA[2]+wA[3];
    int nna = wB[0]+wB[1]+wB[2]+wB[3];
    int pb  = wC[0]+wC[1]+wC[2]+wC[3];
    int nb  = wD[0]+wD[1]+wD[2]+wD[3];

    int excess_pos = (npa > 128) ? (npa - 128) : 0;
    int n_pos_f = npa - excess_pos;
    int n_neg_req = 256 - n_pos_f;
    int excess_neg = (nna > n_neg_req) ? (nna - n_neg_req) : 0;
    int n_neg_f = nna - excess_neg;

    // own-chunk ranks + compaction
    int i = b * 256 + t;
    int lab = -2;
    if (i < N_ANCH) {
        float amax = __uint_as_float(akhi[2 * i]);
        bool fl = (fbm[i >> 5] >> (i & 31)) & 1u;
        lab = (amax < 0.3f) ? 0 : ((amax >= 0.7f || fl) ? 1 : -1);
    }
    bool f1 = (lab == 1), f0 = (lab == 0);
    unsigned long long b1 = __ballot(f1), b0v = __ballot(f0);
    unsigned long long pm = (2ull << lane) - 1ull;   // inclusive mask
    int r1 = __popcll(b1 & pm), r0 = __popcll(b0v & pm);
    if (lane == 0) { wps[wid] = __popcll(b1); wns[wid] = __popcll(b0v); }
    __syncthreads();
    int p1 = 0, p0 = 0, cpB = 0, cnB = 0;
    for (int w = 0; w < 4; ++w) {
        int v1 = wps[w], v0 = wns[w];
        cpB += v1; cnB += v0;
        if (w < wid) { p1 += v1; p0 += v0; }
    }
    int thp = excess_pos - pb; thp = (thp < 0) ? 0 : thp;
    int thn = excess_neg - nb; thn = (thn < 0) ? 0 : thn;
    if (f1) {
        int L = p1 + r1;                 // 1-based local inclusive rank
        if (L > thp) {
            int slot = L - thp - 1;
            sPosI[slot] = i;
            unsigned am = ~(unsigned)(ws->akey[i]);
            sPosBox[slot] = ((const float4*)gtb)[am];
            sPosCls[slot] = gtl[am] + 5;
        }
    }
    if (f0) {
        int L = p0 + r0;
        if (L > thn) sNegI[L - thn - 1] = i;
    }
    __syncthreads();
    int nP = cpB - thp; nP = (nP < 0) ? 0 : nP;
    int nN = cnB - thn; nN = (nN < 0) ? 0 : nN;

    // column-parallel loss over block-local survivors (coalesced pred reads)
    float acc_a = 0.f, acc_c = 0.f, acc_n = 0.f;
    int nT = nP * N_OUTC;
    for (int u = t; u < nT; u += 256) {
        int pi = u / N_OUTC, col = u - pi * N_OUTC;
        float p = pred[sPosI[pi] * N_OUTC + col];
        if (col < 4) {
            float d = p - ((const float*)&sPosBox[pi])[col];
            acc_a += d * d;
        } else if (col == 4) {
            acc_a += bce(p, 1.0f);
        } else {
            acc_c += bce(p, (col == sPosCls[pi]) ? 1.0f : 0.0f);
        }
    }
    for (int u = t; u < nN; u += 256)
        acc_n += bce(pred[sNegI[u] * N_OUTC + 4], 0.0f);

    for (int o = 32; o; o >>= 1) {
        acc_a += __shfl_down(acc_a, o);
        acc_c += __shfl_down(acc_c, o);
        acc_n += __shfl_down(acc_n, o);
    }
    if (lane == 0) { red[wid] = acc_a; red[4 + wid] = acc_c; red[8 + wid] = acc_n; }
    __syncthreads();
    if (t == 0) {
        float A  = red[0] + red[1] + red[2]  + red[3];
        float C  = red[4] + red[5] + red[6]  + red[7];
        float Nn = red[8] + red[9] + red[10] + red[11];
        float np = fmaxf((float)n_pos_f, 1.0f);
        float nn = fmaxf((float)n_neg_f, 1.0f);
        float contrib = A / np + Nn / nn + C / (np * 80.0f);
        if (contrib != 0.0f) atomicAdd(&out[PRED_ELEMS], contrib);
    }
}

extern "C" void kernel_launch(void* const* d_in, const int* in_sizes, int n_in,
                              void* d_out, int out_size, void* d_ws, size_t ws_size,
                              hipStream_t stream) {
    const float* pred   = (const float*)d_in[0];
    const float* gtb    = (const float*)d_in[1];
    const int*   gtl    = (const int*)d_in[2];
    const float* priors = (const float*)d_in[3];
    float* out = (float*)d_out;
    WS* ws = (WS*)d_ws;

    hipMemsetAsync(d_ws, 0, MEMSET_BYTES, stream);
    k_iou<<<dim3(NBLK_IOU), 256, 0, stream>>>(pred, gtb, priors, out, ws);
    k_tail<<<dim3(N_CHUNK), 256, 0, stream>>>(pred, gtb, gtl, ws, out);
}

// Round 8
// 66.422 us; speedup vs baseline: 1.1691x; 1.1691x over previous
//
#include <hip/hip_runtime.h>
#include <math.h>

#define N_ANCH 10647
#define N_GT   2048
#define N_OUTC 85
#define PRED_ELEMS (N_ANCH * N_OUTC)   // 904995
#define PRED_V4    (PRED_ELEMS / 4)    // 226248 (3 tail floats)
#define N_CHUNK    42                  // ceil(10647/256)

// k_iou geometry: 64-entry LDS chunks, ILP-2, big grid for occupancy
#define ABX 21                         // anchor side: 21 x 512 anchors (2/thread)
#define ABY 32                         //              32 x 64-GT chunks
#define NBLK_A (ABX * ABY)             // 672
#define GBX 4                          // gt side: 4 x 512 GTs (2/thread)
#define GBY 167                        //          167 x 64-anchor chunks (pad tail)
#define NBLK_G (GBX * GBY)             // 668
#define NBLK_IOU (NBLK_A + NBLK_G)     // 1340
#define CPY_PER_BLK ((PRED_V4 + NBLK_IOU - 1) / NBLK_IOU)   // 169

struct WS {
    unsigned long long akey[N_ANCH];   // packed (iou_bits<<32)|~gt_idx   (memset 0)
    unsigned long long gkey[N_GT];     // packed (iou_bits<<32)|~anchor_idx (memset 0)
    int cnt_p[N_CHUNK], cnt_n[N_CHUNK];
    unsigned int sync;                 // spin-barrier arrival counter (memset 0)
};

__device__ __forceinline__ float bce(float x, float t) {
    // matches: max(x,0) - x*t + log1p(exp(-|x|))
    return fmaxf(x, 0.0f) - x * t + log1pf(expf(-fabsf(x)));
}

__device__ __forceinline__ unsigned long long packkey(float iou, int idx) {
    return ((unsigned long long)__float_as_uint(iou) << 32) |
           (unsigned)(~(unsigned)idx);
}

// ---------------- K1: pred->out copy + fused IoU reductions ----------------
// Argmax state per slot: (I=inter, S=areaA+areaB, idx); iou = I/(S-I).
// Compare via cross-mult (monotone, denominators > 0); one IEEE div for the
// winner -> bitwise == reference iou value.
__global__ __launch_bounds__(256) void k_iou(const float* __restrict__ pred,
                                             const float* __restrict__ gtb,
                                             const float* __restrict__ priors,
                                             float* __restrict__ out,
                                             WS* __restrict__ ws) {
    int b = blockIdx.x, t = threadIdx.x;
    // distributed pred -> out copy (1 float4 per thread)
    if (t < CPY_PER_BLK) {
        int idx = b * CPY_PER_BLK + t;
        if (idx < PRED_V4)
            ((float4*)out)[idx] = ((const float4*)pred)[idx];
    }
    if (b == 0 && t == 0) {
        out[PRED_ELEMS - 3] = pred[PRED_ELEMS - 3];
        out[PRED_ELEMS - 2] = pred[PRED_ELEMS - 2];
        out[PRED_ELEMS - 1] = pred[PRED_ELEMS - 1];
        out[PRED_ELEMS] = 0.0f;        // k_tail2 atomicAdds into this
    }

    __shared__ float4 sc[64];
    __shared__ float  sa[64];

    if (b < NBLK_A) {
        // ---- anchor side: 2 anchors/thread vs 64 GTs in LDS ----
        int bx = b % ABX, by = b / ABX;
        int jbase = by * 64;
        if (t < 64) {
            float4 v = ((const float4*)gtb)[jbase + t];
            float4 c = make_float4(v.x - v.z*0.5f, v.y - v.w*0.5f,
                                   v.x + v.z*0.5f, v.y + v.w*0.5f);
            sc[t] = c;
            sa[t] = (c.z - c.x) * (c.w - c.y);
        }
        int i0 = bx * 512 + t, i1 = i0 + 256;
        bool v0 = (i0 < N_ANCH), v1 = (i1 < N_ANCH);
        float4 a0 = make_float4(0.f,0.f,0.f,0.f), a1 = a0;
        float aa0 = 0.f, aa1 = 0.f;
        if (v0) {
            float cx = priors[i0*N_OUTC+0], cy = priors[i0*N_OUTC+1];
            float w  = priors[i0*N_OUTC+2], h  = priors[i0*N_OUTC+3];
            a0 = make_float4(cx - w*0.5f, cy - h*0.5f, cx + w*0.5f, cy + h*0.5f);
            aa0 = (a0.z - a0.x) * (a0.w - a0.y);
        }
        if (v1) {
            float cx = priors[i1*N_OUTC+0], cy = priors[i1*N_OUTC+1];
            float w  = priors[i1*N_OUTC+2], h  = priors[i1*N_OUTC+3];
            a1 = make_float4(cx - w*0.5f, cy - h*0.5f, cx + w*0.5f, cy + h*0.5f);
            aa1 = (a1.z - a1.x) * (a1.w - a1.y);
        }
        __syncthreads();
        float I0 = -1.f, S0 = 1.f, I1 = -1.f, S1 = 1.f;
        int bj0 = 0, bj1 = 0;
#pragma unroll 4
        for (int jj = 0; jj < 64; ++jj) {
            float4 g = sc[jj]; float ga = sa[jj];
            float lx = fmaxf(a0.x, g.x), ly = fmaxf(a0.y, g.y);
            float rx = fminf(a0.z, g.z), ry = fminf(a0.w, g.w);
            float In = fmaxf(rx - lx, 0.f) * fmaxf(ry - ly, 0.f);
            float Sn = aa0 + ga;
            bool c = In * S0 > I0 * Sn;      // strict: first index on ties
            I0 = c ? In : I0; S0 = c ? Sn : S0; bj0 = c ? jj : bj0;
            lx = fmaxf(a1.x, g.x); ly = fmaxf(a1.y, g.y);
            rx = fminf(a1.z, g.z); ry = fminf(a1.w, g.w);
            In = fmaxf(rx - lx, 0.f) * fmaxf(ry - ly, 0.f);
            Sn = aa1 + ga;
            c = In * S1 > I1 * Sn;
            I1 = c ? In : I1; S1 = c ? Sn : S1; bj1 = c ? jj : bj1;
        }
        if (v0) atomicMax(&ws->akey[i0], packkey(I0 / (S0 - I0), jbase + bj0));
        if (v1) atomicMax(&ws->akey[i1], packkey(I1 / (S1 - I1), jbase + bj1));
    } else {
        // ---- gt side: 2 GTs/thread vs 64 anchors in LDS ----
        int b2 = b - NBLK_A;
        int bx = b2 % GBX, by = b2 / GBX;
        int ibase = by * 64;
        if (t < 64) {
            int i = ibase + t;
            float4 c = make_float4(0.f, 0.f, 0.f, 0.f);
            float ar = 0.f;
            if (i < N_ANCH) {
                float cx = priors[i*N_OUTC+0], cy = priors[i*N_OUTC+1];
                float w  = priors[i*N_OUTC+2], h  = priors[i*N_OUTC+3];
                c = make_float4(cx - w*0.5f, cy - h*0.5f, cx + w*0.5f, cy + h*0.5f);
                ar = (c.z - c.x) * (c.w - c.y);
            }
            // pads: I=0 -> never wins the strict cross-mult compare vs a real
            // earlier candidate with I >= 0.
            sc[t] = c; sa[t] = ar;
        }
        int j0 = bx * 512 + t, j1 = j0 + 256;
        float4 v = ((const float4*)gtb)[j0];
        float4 g0 = make_float4(v.x - v.z*0.5f, v.y - v.w*0.5f,
                                v.x + v.z*0.5f, v.y + v.w*0.5f);
        float ga0 = (g0.z - g0.x) * (g0.w - g0.y);
        v = ((const float4*)gtb)[j1];
        float4 g1 = make_float4(v.x - v.z*0.5f, v.y - v.w*0.5f,
                                v.x + v.z*0.5f, v.y + v.w*0.5f);
        float ga1 = (g1.z - g1.x) * (g1.w - g1.y);
        __syncthreads();
        float I0 = -1.f, S0 = 1.f, I1 = -1.f, S1 = 1.f;
        int bi0 = 0, bi1 = 0;
#pragma unroll 4
        for (int ii = 0; ii < 64; ++ii) {
            float4 a = sc[ii]; float aa = sa[ii];
            float lx = fmaxf(a.x, g0.x), ly = fmaxf(a.y, g0.y);
            float rx = fminf(a.z, g0.z), ry = fminf(a.w, g0.w);
            float In = fmaxf(rx - lx, 0.f) * fmaxf(ry - ly, 0.f);
            float Sn = aa + ga0;
            bool c = In * S0 > I0 * Sn;
            I0 = c ? In : I0; S0 = c ? Sn : S0; bi0 = c ? ii : bi0;
            lx = fmaxf(a.x, g1.x); ly = fmaxf(a.y, g1.y);
            rx = fminf(a.z, g1.z); ry = fminf(a.w, g1.w);
            In = fmaxf(rx - lx, 0.f) * fmaxf(ry - ly, 0.f);
            Sn = aa + ga1;
            c = In * S1 > I1 * Sn;
            I1 = c ? In : I1; S1 = c ? Sn : S1; bi1 = c ? ii : bi1;
        }
        atomicMax(&ws->gkey[j0], packkey(I0 / (S0 - I0), ibase + bi0));
        atomicMax(&ws->gkey[j1], packkey(I1 / (S1 - I1), ibase + bi1));
    }
}

// ---------------- K2: fused tail with device spin-barrier ----------------
// 42 blocks (all co-resident on 256 CUs -> barrier is safe).
// A: own-chunk labels+counts (gkey scan for flags), publish counts (agent scope)
// B: spin until all 42 arrived, read the 84 counters (agent scope)
// C: demote-first ranks + compact survivors to LDS
// D: column-parallel loss, pre-normalized atomicAdd into out[PRED_ELEMS]
__global__ __launch_bounds__(256) void k_tail2(const float* __restrict__ pred,
                                               const float* __restrict__ gtb,
                                               const int* __restrict__ gtl,
                                               WS* __restrict__ ws,
                                               float* __restrict__ out) {
    __shared__ int sFlg[256];
    __shared__ int wA[4], wB[4];
    __shared__ int wps[4], wns[4];
    __shared__ int sCp[N_CHUNK], sCn[N_CHUNK];
    __shared__ int    sPosI[256];
    __shared__ float4 sPosBox[256];
    __shared__ int    sPosCls[256];
    __shared__ int    sNegI[256];
    __shared__ float  red[12];
    int b = blockIdx.x, t = threadIdx.x, lane = t & 63, wid = t >> 6;
    int base = b * 256;

    // ---- A: own-chunk is_gt_max flags + labels + counts ----
    sFlg[t] = 0;
    __syncthreads();
    for (int j = t; j < N_GT; j += 256) {
        int ai = (int)(~(unsigned)(ws->gkey[j]));
        int rel = ai - base;
        if ((unsigned)rel < 256u) sFlg[rel] = 1;   // benign same-value races
    }
    __syncthreads();
    int i = base + t;
    int lab = -2;
    if (i < N_ANCH) {
        float amax = __uint_as_float((unsigned)(ws->akey[i] >> 32));
        lab = (amax < 0.3f) ? 0 : ((amax >= 0.7f || sFlg[t]) ? 1 : -1);
    }
    bool f1 = (lab == 1), f0 = (lab == 0);
    unsigned long long b1 = __ballot(f1), b0v = __ballot(f0);
    if (lane == 0) { wA[wid] = __popcll(b1); wB[wid] = __popcll(b0v); }
    __syncthreads();
    if (t == 0) {
        int cp = wA[0] + wA[1] + wA[2] + wA[3];
        int cn = wB[0] + wB[1] + wB[2] + wB[3];
        __hip_atomic_store(&ws->cnt_p[b], cp, __ATOMIC_RELAXED, __HIP_MEMORY_SCOPE_AGENT);
        __hip_atomic_store(&ws->cnt_n[b], cn, __ATOMIC_RELAXED, __HIP_MEMORY_SCOPE_AGENT);
        __hip_atomic_fetch_add(&ws->sync, 1u, __ATOMIC_RELEASE, __HIP_MEMORY_SCOPE_AGENT);
        // ---- B: spin until all blocks have published ----
        while (__hip_atomic_load(&ws->sync, __ATOMIC_ACQUIRE, __HIP_MEMORY_SCOPE_AGENT)
               < (unsigned)N_CHUNK)
            __builtin_amdgcn_s_sleep(2);
    }
    __syncthreads();
    if (t < N_CHUNK) {
        sCp[t] = __hip_atomic_load(&ws->cnt_p[t], __ATOMIC_ACQUIRE, __HIP_MEMORY_SCOPE_AGENT);
        sCn[t] = __hip_atomic_load(&ws->cnt_n[t], __ATOMIC_ACQUIRE, __HIP_MEMORY_SCOPE_AGENT);
    }
    __syncthreads();
    int npa = 0, nna = 0, pb = 0, nb = 0;
#pragma unroll
    for (int c = 0; c < N_CHUNK; ++c) {
        int cp = sCp[c], cn = sCn[c];
        if (c < b) { pb += cp; nb += cn; }
        npa += cp; nna += cn;
    }
    int excess_pos = (npa > 128) ? (npa - 128) : 0;
    int n_pos_f = npa - excess_pos;
    int n_neg_req = 256 - n_pos_f;
    int excess_neg = (nna > n_neg_req) ? (nna - n_neg_req) : 0;
    int n_neg_f = nna - excess_neg;

    // ---- C: own-chunk ranks + compaction (survivors = suffix of ranks) ----
    unsigned long long pm = (2ull << lane) - 1ull;   // inclusive mask
    int r1 = __popcll(b1 & pm), r0 = __popcll(b0v & pm);
    if (lane == 0) { wps[wid] = __popcll(b1); wns[wid] = __popcll(b0v); }
    __syncthreads();
    int p1 = 0, p0 = 0, cpB = 0, cnB = 0;
    for (int w = 0; w < 4; ++w) {
        int v1 = wps[w], v0 = wns[w];
        cpB += v1; cnB += v0;
        if (w < wid) { p1 += v1; p0 += v0; }
    }
    int thp = excess_pos - pb; thp = (thp < 0) ? 0 : thp;
    int thn = excess_neg - nb; thn = (thn < 0) ? 0 : thn;
    if (f1) {
        int L = p1 + r1;                 // 1-based local inclusive rank
        if (L > thp) {
            int slot = L - thp - 1;
            sPosI[slot] = i;
            unsigned am = ~(unsigned)(ws->akey[i]);
            sPosBox[slot] = ((const float4*)gtb)[am];
            sPosCls[slot] = gtl[am] + 5;
        }
    }
    if (f0) {
        int L = p0 + r0;
        if (L > thn) sNegI[L - thn - 1] = i;
    }
    __syncthreads();
    int nP = cpB - thp; nP = (nP < 0) ? 0 : nP;
    int nN = cnB - thn; nN = (nN < 0) ? 0 : nN;

    // ---- D: column-parallel loss over block-local survivors ----
    float acc_a = 0.f, acc_c = 0.f, acc_n = 0.f;
    int nT = nP * N_OUTC;
    for (int u = t; u < nT; u += 256) {
        int pi = u / N_OUTC, col = u - pi * N_OUTC;
        float p = pred[sPosI[pi] * N_OUTC + col];
        if (col < 4) {
            float d = p - ((const float*)&sPosBox[pi])[col];
            acc_a += d * d;
        } else if (col == 4) {
            acc_a += bce(p, 1.0f);
        } else {
            acc_c += bce(p, (col == sPosCls[pi]) ? 1.0f : 0.0f);
        }
    }
    for (int u = t; u < nN; u += 256)
        acc_n += bce(pred[sNegI[u] * N_OUTC + 4], 0.0f);

    for (int o = 32; o; o >>= 1) {
        acc_a += __shfl_down(acc_a, o);
        acc_c += __shfl_down(acc_c, o);
        acc_n += __shfl_down(acc_n, o);
    }
    if (lane == 0) { red[wid] = acc_a; red[4 + wid] = acc_c; red[8 + wid] = acc_n; }
    __syncthreads();
    if (t == 0) {
        float A  = red[0] + red[1] + red[2]  + red[3];
        float C  = red[4] + red[5] + red[6]  + red[7];
        float Nn = red[8] + red[9] + red[10] + red[11];
        float np = fmaxf((float)n_pos_f, 1.0f);
        float nn = fmaxf((float)n_neg_f, 1.0f);
        float contrib = A / np + Nn / nn + C / (np * 80.0f);
        if (contrib != 0.0f) atomicAdd(&out[PRED_ELEMS], contrib);
    }
}

extern "C" void kernel_launch(void* const* d_in, const int* in_sizes, int n_in,
                              void* d_out, int out_size, void* d_ws, size_t ws_size,
                              hipStream_t stream) {
    const float* pred   = (const float*)d_in[0];
    const float* gtb    = (const float*)d_in[1];
    const int*   gtl    = (const int*)d_in[2];
    const float* priors = (const float*)d_in[3];
    float* out = (float*)d_out;
    WS* ws = (WS*)d_ws;

    hipMemsetAsync(d_ws, 0, sizeof(WS), stream);
    k_iou<<<dim3(NBLK_IOU), 256, 0, stream>>>(pred, gtb, priors, out, ws);
    k_tail2<<<dim3(N_CHUNK), 256, 0, stream>>>(pred, gtb, gtl, ws, out);
}